// Round 1
// baseline (956.230 us; speedup 1.0000x reference)
//
#include <hip/hip_runtime.h>

// ---------------------------------------------------------------------------
// MHSA (faithful to reference: softmax over HEADS at each position).
//   Q = q@Wq^T+bq ; K,V likewise          -> bf16 GEMMs (M=16384,N=K=2048)
//   per (b,s): scores[i][j] = <Q[b,s,i,:],K[b,s,j,:]>/sqrt(128); softmax over j
//              x[i][:] = sum_j attn[i][j] V[b,s,j,:]
//   X2 = permute(x) rows r=h*256+s/16, cols c=(s%16)*128+dh  (bf16)
//   out = X2@Wo^T+bo (fp32) ; d_out = [out | attention]
// ---------------------------------------------------------------------------

#define DEV __device__ __forceinline__

using short8  = __attribute__((ext_vector_type(8))) short;
using ushort8 = __attribute__((ext_vector_type(8))) unsigned short;
using f32x4   = __attribute__((ext_vector_type(4))) float;

constexpr int BATCH = 4, SEQ = 4096, DIM = 2048, NH = 16, DHD = 128;
constexpr int GM = BATCH * SEQ;   // 16384 rows
constexpr int GN = DIM, GK = DIM; // 2048

DEV unsigned short f2bf(float f) {
  unsigned int u = __builtin_bit_cast(unsigned int, f);
  u += 0x7FFFu + ((u >> 16) & 1u);   // RNE
  return (unsigned short)(u >> 16);
}
DEV float bf2f(unsigned short h) {
  unsigned int u = ((unsigned int)h) << 16;
  return __builtin_bit_cast(float, u);
}

DEV void gload16(const void* g, void* l) {
  __builtin_amdgcn_global_load_lds(
      (const __attribute__((address_space(1))) void*)g,
      (__attribute__((address_space(3))) void*)l, 16, 0, 0);
}

// ---------------- fp32 -> bf16 conversion (elementwise) --------------------
__global__ void cvt_f32_bf16(const float* __restrict__ src,
                             unsigned short* __restrict__ dst, int n) {
  int i = (blockIdx.x * blockDim.x + threadIdx.x) * 4;
  if (i >= n) return;
  f32x4 f = *(const f32x4*)(src + i);
  ushort4 o;
  o.x = f2bf(f[0]); o.y = f2bf(f[1]); o.z = f2bf(f[2]); o.w = f2bf(f[3]);
  *(ushort4*)(dst + i) = o;
}

// ---------------- GEMM: C[M,N] = A[M,K] * B[N,K]^T + bias -----------------
// m97 structure: 128x128 tile, BK=32, 4 waves (2x2), 4x4 16x16x32 MFMA frags.
template <bool AF32, bool OUTF32>
__global__ __launch_bounds__(256)
void gemm_bt(const void* __restrict__ Ap, const unsigned short* __restrict__ Bp,
             const float* __restrict__ bias, void* __restrict__ Cp) {
  constexpr int BM = 128, BN = 128, BK = 32;
  __shared__ unsigned short As[BM * BK];
  __shared__ unsigned short Bs[BN * BK];

  const int tid  = threadIdx.x;
  const int lane = tid & 63;
  const int wv   = tid >> 6;

  // XCD-aware bijective swizzle (nwg = 2048, divisible by 8)
  constexpr int NWG = (GM / BM) * (GN / BN);  // 2048
  int bid = (int)blockIdx.x;
  bid = (bid & 7) * (NWG >> 3) + (bid >> 3);
  const int mt = bid >> 4;          // GN/BN = 16 n-tiles
  const int nt = bid & 15;
  const int bm0 = mt * BM, bn0 = nt * BN;

  const int wr = wv >> 1, wc = wv & 1;
  const int r16 = lane & 15, kblk = lane >> 4;

  f32x4 acc[4][4] = {};

  const int srow = lane >> 2;        // 0..15 within 16-row chunk
  const int scol = (lane & 3) * 8;   // k element offset of this lane's 16B

  for (int k0 = 0; k0 < GK; k0 += BK) {
    if (k0) __syncthreads();
    // ---- stage B (bf16, global_load_lds width 16) ----
#pragma unroll
    for (int c = 0; c < 2; ++c) {
      const int chunk = wv * 2 + c;
      const unsigned short* g =
          Bp + (size_t)(bn0 + chunk * 16 + srow) * GK + (k0 + scol);
      gload16(g, &Bs[chunk * 512]);
    }
    // ---- stage A ----
    if constexpr (AF32) {
      const float* Af = (const float*)Ap;
      const int arow = tid >> 1;
      const int ak = (tid & 1) * 16;
      const f32x4* g4 = (const f32x4*)(Af + (size_t)(bm0 + arow) * GK + k0 + ak);
      f32x4 f[4];
      f[0] = g4[0]; f[1] = g4[1]; f[2] = g4[2]; f[3] = g4[3];
      ushort8 p0, p1;
#pragma unroll
      for (int j = 0; j < 8; ++j) {
        p0[j] = f2bf(f[j >> 2][j & 3]);
        p1[j] = f2bf(f[2 + (j >> 2)][j & 3]);
      }
      *(ushort8*)&As[arow * BK + ak]     = p0;
      *(ushort8*)&As[arow * BK + ak + 8] = p1;
    } else {
#pragma unroll
      for (int c = 0; c < 2; ++c) {
        const int chunk = wv * 2 + c;
        const unsigned short* g = (const unsigned short*)Ap +
            (size_t)(bm0 + chunk * 16 + srow) * GK + (k0 + scol);
        gload16(g, &As[chunk * 512]);
      }
    }
    __syncthreads();
    // ---- compute ----
    short8 af[4], bf[4];
#pragma unroll
    for (int m = 0; m < 4; ++m)
      af[m] = *(const short8*)&As[(wr * 64 + m * 16 + r16) * BK + kblk * 8];
#pragma unroll
    for (int n = 0; n < 4; ++n)
      bf[n] = *(const short8*)&Bs[(wc * 64 + n * 16 + r16) * BK + kblk * 8];
#pragma unroll
    for (int m = 0; m < 4; ++m)
#pragma unroll
      for (int n = 0; n < 4; ++n)
        acc[m][n] = __builtin_amdgcn_mfma_f32_16x16x32_bf16(af[m], bf[n],
                                                            acc[m][n], 0, 0, 0);
  }
  // ---- epilogue: C row=(lane>>4)*4+i, col=lane&15 (m89-verified) ----
  const int rb = (lane >> 4) * 4;
#pragma unroll
  for (int m = 0; m < 4; ++m) {
#pragma unroll
    for (int i = 0; i < 4; ++i) {
      const size_t row = bm0 + wr * 64 + m * 16 + rb + i;
#pragma unroll
      for (int n = 0; n < 4; ++n) {
        const int col = bn0 + wc * 64 + n * 16 + r16;
        float v = acc[m][n][i] + bias[col];
        if constexpr (OUTF32)
          ((float*)Cp)[row * GN + col] = v;
        else
          ((unsigned short*)Cp)[row * GN + col] = f2bf(v);
      }
    }
  }
}

// ---------------- per-position attention (softmax over heads) -------------
using u16x8 = __attribute__((ext_vector_type(8))) unsigned short;

__global__ __launch_bounds__(256)
void attn_kernel(const unsigned short* __restrict__ Qb,
                 const unsigned short* __restrict__ Kb,
                 const unsigned short* __restrict__ Vb,
                 float* __restrict__ attnOut,
                 unsigned short* __restrict__ X2) {
  __shared__ float qf[16 * 128];
  __shared__ float kf[16 * 132];  // +4 pad: kills 16-way bank conflict on j
  __shared__ float vf[16 * 128];
  __shared__ float sc[256];

  const int t = threadIdx.x;
  const int p = blockIdx.x;           // (b*SEQ + s)
  const size_t rowoff = (size_t)p * DIM;

  {  // load q,k,v rows (bf16x8 per thread each), convert to f32 in LDS
    const int e = t * 8;
    u16x8 qv = *(const u16x8*)(Qb + rowoff + e);
    u16x8 kv = *(const u16x8*)(Kb + rowoff + e);
    u16x8 vv = *(const u16x8*)(Vb + rowoff + e);
    const int r = t >> 4, c = (t & 15) * 8;
#pragma unroll
    for (int j = 0; j < 8; ++j) qf[r * 128 + c + j] = bf2f(qv[j]);
#pragma unroll
    for (int j = 0; j < 8; ++j) kf[r * 132 + c + j] = bf2f(kv[j]);
#pragma unroll
    for (int j = 0; j < 8; ++j) vf[r * 128 + c + j] = bf2f(vv[j]);
  }
  __syncthreads();

  const int i = t >> 4, j = t & 15;
  float s = 0.f;
#pragma unroll
  for (int d4 = 0; d4 < 32; ++d4) {
    f32x4 q4 = *(const f32x4*)&qf[i * 128 + d4 * 4];
    f32x4 k4 = *(const f32x4*)&kf[j * 132 + d4 * 4];
    s = fmaf(q4[0], k4[0], fmaf(q4[1], k4[1], fmaf(q4[2], k4[2], fmaf(q4[3], k4[3], s))));
  }
  s *= 0.08838834764831845f;  // 1/sqrt(128)

  float mx = s;
#pragma unroll
  for (int off = 8; off; off >>= 1) mx = fmaxf(mx, __shfl_xor(mx, off, 16));
  float ex = __expf(s - mx);
  float sum = ex;
#pragma unroll
  for (int off = 8; off; off >>= 1) sum += __shfl_xor(sum, off, 16);
  float a = ex / sum;

  attnOut[(size_t)p * 256 + t] = a;   // [B,S,H,H] fp32, coalesced
  sc[t] = a;
  __syncthreads();

  // PV: this thread -> head i, dh block j*8
  const int dh0 = j * 8;
  float o[8] = {};
#pragma unroll
  for (int jj = 0; jj < 16; ++jj) {
    float aij = sc[i * 16 + jj];
#pragma unroll
    for (int e2 = 0; e2 < 8; ++e2)
      o[e2] = fmaf(aij, vf[jj * 128 + dh0 + e2], o[e2]);
  }
  // scatter into X2: row = h*256 + s/16, col = (s%16)*128 + dh
  const int b = p >> 12, spos = p & 4095;
  const int row = i * 256 + (spos >> 4);
  const int col = ((spos & 15) << 7) + dh0;
  ushort8 pk;
#pragma unroll
  for (int e2 = 0; e2 < 8; ++e2) pk[e2] = f2bf(o[e2]);
  *(ushort8*)(X2 + (size_t)b * (SEQ * DIM) + (size_t)row * DIM + col) = pk;
}

// ---------------------------------------------------------------------------
extern "C" void kernel_launch(void* const* d_in, const int* in_sizes, int n_in,
                              void* d_out, int out_size, void* d_ws,
                              size_t ws_size, hipStream_t stream) {
  const float* q  = (const float*)d_in[0];
  const float* k  = (const float*)d_in[1];
  const float* v  = (const float*)d_in[2];
  const float* Wq = (const float*)d_in[3];
  const float* bq = (const float*)d_in[4];
  const float* Wk = (const float*)d_in[5];
  const float* bk = (const float*)d_in[6];
  const float* Wv = (const float*)d_in[7];
  const float* bv = (const float*)d_in[8];
  const float* Wo = (const float*)d_in[9];
  const float* bo = (const float*)d_in[10];

  const size_t NE = (size_t)GM * GK;  // 33,554,432 activation elems
  const size_t WE = (size_t)GK * GN;  //  4,194,304 weight elems

  unsigned short* ws16 = (unsigned short*)d_ws;
  unsigned short* Wq_b = ws16;
  unsigned short* Wk_b = Wq_b + WE;
  unsigned short* Wv_b = Wk_b + WE;
  unsigned short* Wo_b = Wv_b + WE;
  unsigned short* Qb   = Wo_b + WE;
  unsigned short* Kb   = Qb + NE;
  unsigned short* Vb   = Kb + NE;
  unsigned short* X2   = Vb + NE;
  unsigned short* Qin  = X2 + NE;   // only used on big-ws path
  unsigned short* Kin  = Qin + NE;
  unsigned short* Vin  = Kin + NE;

  const size_t need_small = (4 * WE + 4 * NE) * 2;       // ~288 MB
  const size_t need_big   = need_small + 3 * NE * 2;     // ~480 MB
  const bool big = ws_size >= need_big;

  float* outMain = (float*)d_out;
  float* attnOut = outMain + (size_t)GM * GN;  // +33,554,432

  // 1) convert weights
  cvt_f32_bf16<<<WE / 1024, 256, 0, stream>>>(Wq, Wq_b, (int)WE);
  cvt_f32_bf16<<<WE / 1024, 256, 0, stream>>>(Wk, Wk_b, (int)WE);
  cvt_f32_bf16<<<WE / 1024, 256, 0, stream>>>(Wv, Wv_b, (int)WE);
  cvt_f32_bf16<<<WE / 1024, 256, 0, stream>>>(Wo, Wo_b, (int)WE);

  constexpr int GEMM_GRID = (GM / 128) * (GN / 128);  // 2048

  if (big) {
    // 2) convert activations to bf16, then pure global_load_lds GEMMs
    cvt_f32_bf16<<<NE / 1024, 256, 0, stream>>>(q, Qin, (int)NE);
    cvt_f32_bf16<<<NE / 1024, 256, 0, stream>>>(k, Kin, (int)NE);
    cvt_f32_bf16<<<NE / 1024, 256, 0, stream>>>(v, Vin, (int)NE);
    gemm_bt<false, false><<<GEMM_GRID, 256, 0, stream>>>(Qin, Wq_b, bq, Qb);
    gemm_bt<false, false><<<GEMM_GRID, 256, 0, stream>>>(Kin, Wk_b, bk, Kb);
    gemm_bt<false, false><<<GEMM_GRID, 256, 0, stream>>>(Vin, Wv_b, bv, Vb);
  } else {
    // reg-staged fp32 A with in-flight conversion
    gemm_bt<true, false><<<GEMM_GRID, 256, 0, stream>>>(q, Wq_b, bq, Qb);
    gemm_bt<true, false><<<GEMM_GRID, 256, 0, stream>>>(k, Wk_b, bk, Kb);
    gemm_bt<true, false><<<GEMM_GRID, 256, 0, stream>>>(v, Wv_b, bv, Vb);
  }

  // 3) per-position attention + permuted scatter
  attn_kernel<<<GM, 256, 0, stream>>>(Qb, Kb, Vb, attnOut, X2);

  // 4) output projection (fp32 out)
  gemm_bt<false, true><<<GEMM_GRID, 256, 0, stream>>>(X2, Wo_b, bo, outMain);
}

// Round 2
// 827.889 us; speedup vs baseline: 1.1550x; 1.1550x over previous
//
#include <hip/hip_runtime.h>

// ---------------------------------------------------------------------------
// MHSA (faithful: softmax over HEADS at each position).
//   Q/K/V/out projections: 256x256-tile 8-wave 4-phase MFMA GEMM (bf16)
//   attention: per-position 16x16 softmax-over-heads + PV, permuted scatter
// ---------------------------------------------------------------------------

#define DEV __device__ __forceinline__

using short8  = __attribute__((ext_vector_type(8))) short;
using ushort8 = __attribute__((ext_vector_type(8))) unsigned short;
using f32x4   = __attribute__((ext_vector_type(4))) float;
using u16x8   = __attribute__((ext_vector_type(8))) unsigned short;

constexpr int BATCH = 4, SEQ = 4096, DIM = 2048;
constexpr int GM = BATCH * SEQ;   // 16384
constexpr int GN = DIM, GK = DIM; // 2048

DEV unsigned short f2bf(float f) {
  unsigned int u = __builtin_bit_cast(unsigned int, f);
  u += 0x7FFFu + ((u >> 16) & 1u);   // RNE
  return (unsigned short)(u >> 16);
}
DEV float bf2f(unsigned short h) {
  unsigned int u = ((unsigned int)h) << 16;
  return __builtin_bit_cast(float, u);
}

DEV void gload16(const void* g, void* l) {
  __builtin_amdgcn_global_load_lds(
      (const __attribute__((address_space(1))) void*)g,
      (__attribute__((address_space(3))) void*)l, 16, 0, 0);
}

#define BAR    __builtin_amdgcn_s_barrier()
#define LGKM0  asm volatile("s_waitcnt lgkmcnt(0)" ::: "memory")
#define VMCNT4 asm volatile("s_waitcnt vmcnt(4)" ::: "memory")
#define SCHED0 __builtin_amdgcn_sched_barrier(0)

// ---------------- fp32 -> bf16 conversion ---------------------------------
__global__ void cvt_f32_bf16(const float* __restrict__ src,
                             unsigned short* __restrict__ dst, int n) {
  int i = (blockIdx.x * blockDim.x + threadIdx.x) * 4;
  if (i >= n) return;
  f32x4 f = *(const f32x4*)(src + i);
  ushort4 o;
  o.x = f2bf(f[0]); o.y = f2bf(f[1]); o.z = f2bf(f[2]); o.w = f2bf(f[3]);
  *(ushort4*)(dst + i) = o;
}

// ---------------- 256^2 8-wave 4-phase GEMM: C = A[M,K] * B[N,K]^T + bias --
// LDS: 2x(A 256x64 + B 256x64) bf16 = 128 KiB, XOR-swizzled (byte^=(row&7)<<4).
// Waves: 2(M)x4(N); per-wave 128x64 output; acc[8][4] f32x4.
// Per K-tile: 4 phases x 16 MFMA (one quadrant each). Counted vmcnt(4) once
// per K-tile: B(t+1) issued ph0-1, A(t+2) issued ph2-3 -> at ph3 wait, the
// 8 oldest (A(t+1)+B(t+1)) drain, 4 stay in flight.
template <bool OUTF32>
__global__ __launch_bounds__(512)
void gemm256(const unsigned short* __restrict__ Ap,
             const unsigned short* __restrict__ Bp,
             const float* __restrict__ bias, void* __restrict__ Cp) {
  constexpr int BK = 64, KT = GK / BK;   // 32 K-tiles
  __shared__ unsigned short As[2][256 * BK];
  __shared__ unsigned short Bs[2][256 * BK];

  const int tid  = threadIdx.x;
  const int lane = tid & 63;
  const int wv   = tid >> 6;
  const int wm   = wv >> 2, wn = wv & 3;

  // XCD-aware bijective swizzle; nwg=512, each XCD owns one nt column.
  int bid = (int)blockIdx.x;
  int swz = (bid & 7) * 64 + (bid >> 3);
  const int mt = swz & 63, nt = swz >> 6;
  const int bm0 = mt * 256, bn0 = nt * 256;

  // staging precompute: round r dest byte d (linear), source = swz(d)
  int dstoff[4];
  size_t offA[4], offB[4];
#pragma unroll
  for (int r = 0; r < 4; ++r) {
    int d = tid * 16 + r * 8192;
    int s = d ^ (((d >> 7) & 7) << 4);
    int row = s >> 7, col = (s & 127) >> 1;
    dstoff[r] = d;
    offA[r] = (size_t)(bm0 + row) * GK + col;
    offB[r] = (size_t)(bn0 + row) * GK + col;
  }

  const int r16 = lane & 15, kb = (lane >> 4) * 16;
  const int arow = wm * 128 + r16;   // + m*16 (+64 for hi half)
  const int brow = wn * 64 + r16;    // + n*16 (+32 for hi half)

  f32x4 acc[8][4] = {};
  short8 af[4][2], bl[2][2], bh[2][2];

  auto stA = [&](int buf, int kt, int r) {
    gload16(Ap + offA[r] + (size_t)kt * BK, (char*)&As[buf][0] + dstoff[r]);
  };
  auto stB = [&](int buf, int kt, int r) {
    gload16(Bp + offB[r] + (size_t)kt * BK, (char*)&Bs[buf][0] + dstoff[r]);
  };
  auto ldf = [&](const unsigned short* base, int row, int ks) -> short8 {
    int a = (row * 128 + ks * 64 + kb) ^ ((row & 7) << 4);
    return *(const short8*)((const char*)base + a);
  };

  // ---- prologue: A(0),B(0) -> buf0 ; A(1) -> buf1 ----
#pragma unroll
  for (int r = 0; r < 4; ++r) stA(0, 0, r);
#pragma unroll
  for (int r = 0; r < 4; ++r) stB(0, 0, r);
#pragma unroll
  for (int r = 0; r < 4; ++r) stA(1, 1, r);
  VMCNT4;   // A(0)+B(0) resident; A(1) in flight
  BAR;

  for (int kt = 0; kt < KT; ++kt) {
    const int cb = kt & 1, nb = cb ^ 1;
    const unsigned short* Ab = &As[cb][0];
    const unsigned short* Bb = &Bs[cb][0];

    // ===== Phase 0: Q(mlo,nlo) =====
#pragma unroll
    for (int m = 0; m < 4; ++m) {
      af[m][0] = ldf(Ab, arow + m * 16, 0);
      af[m][1] = ldf(Ab, arow + m * 16, 1);
    }
#pragma unroll
    for (int n = 0; n < 2; ++n) {
      bl[n][0] = ldf(Bb, brow + n * 16, 0);
      bl[n][1] = ldf(Bb, brow + n * 16, 1);
    }
    if (kt + 1 < KT) { stB(nb, kt + 1, 0); stB(nb, kt + 1, 1); }
    BAR; LGKM0; SCHED0;
    __builtin_amdgcn_s_setprio(1);
#pragma unroll
    for (int m = 0; m < 4; ++m)
#pragma unroll
      for (int n = 0; n < 2; ++n) {
        acc[m][n] = __builtin_amdgcn_mfma_f32_16x16x32_bf16(af[m][0], bl[n][0], acc[m][n], 0, 0, 0);
        acc[m][n] = __builtin_amdgcn_mfma_f32_16x16x32_bf16(af[m][1], bl[n][1], acc[m][n], 0, 0, 0);
      }
    __builtin_amdgcn_s_setprio(0);
    BAR;

    // ===== Phase 1: Q(mlo,nhi) =====
#pragma unroll
    for (int n = 0; n < 2; ++n) {
      bh[n][0] = ldf(Bb, brow + 32 + n * 16, 0);
      bh[n][1] = ldf(Bb, brow + 32 + n * 16, 1);
    }
    if (kt + 1 < KT) { stB(nb, kt + 1, 2); stB(nb, kt + 1, 3); }
    BAR; LGKM0; SCHED0;
    __builtin_amdgcn_s_setprio(1);
#pragma unroll
    for (int m = 0; m < 4; ++m)
#pragma unroll
      for (int n = 0; n < 2; ++n) {
        acc[m][2 + n] = __builtin_amdgcn_mfma_f32_16x16x32_bf16(af[m][0], bh[n][0], acc[m][2 + n], 0, 0, 0);
        acc[m][2 + n] = __builtin_amdgcn_mfma_f32_16x16x32_bf16(af[m][1], bh[n][1], acc[m][2 + n], 0, 0, 0);
      }
    __builtin_amdgcn_s_setprio(0);
    BAR;

    // ===== Phase 2: Q(mhi,nhi) =====
#pragma unroll
    for (int m = 0; m < 4; ++m) {
      af[m][0] = ldf(Ab, arow + 64 + m * 16, 0);
      af[m][1] = ldf(Ab, arow + 64 + m * 16, 1);
    }
    // A(kt+2) rounds covering mlo rows (r0: 0-63, r2: 128-191) -> current buf
    if (kt + 2 < KT) { stA(cb, kt + 2, 0); stA(cb, kt + 2, 2); }
    BAR; LGKM0; SCHED0;
    __builtin_amdgcn_s_setprio(1);
#pragma unroll
    for (int m = 0; m < 4; ++m)
#pragma unroll
      for (int n = 0; n < 2; ++n) {
        acc[4 + m][2 + n] = __builtin_amdgcn_mfma_f32_16x16x32_bf16(af[m][0], bh[n][0], acc[4 + m][2 + n], 0, 0, 0);
        acc[4 + m][2 + n] = __builtin_amdgcn_mfma_f32_16x16x32_bf16(af[m][1], bh[n][1], acc[4 + m][2 + n], 0, 0, 0);
      }
    __builtin_amdgcn_s_setprio(0);
    BAR;

    // ===== Phase 3: Q(mhi,nlo) =====
    if (kt + 2 < KT) { stA(cb, kt + 2, 1); stA(cb, kt + 2, 3); }
    VMCNT4;   // drain A(kt+1)+B(kt+1); keep A(kt+2) in flight
    BAR;
    __builtin_amdgcn_s_setprio(1);
#pragma unroll
    for (int m = 0; m < 4; ++m)
#pragma unroll
      for (int n = 0; n < 2; ++n) {
        acc[4 + m][n] = __builtin_amdgcn_mfma_f32_16x16x32_bf16(af[m][0], bl[n][0], acc[4 + m][n], 0, 0, 0);
        acc[4 + m][n] = __builtin_amdgcn_mfma_f32_16x16x32_bf16(af[m][1], bl[n][1], acc[4 + m][n], 0, 0, 0);
      }
    __builtin_amdgcn_s_setprio(0);
    BAR;
  }

  // ---- epilogue ----
  float bs[4];
#pragma unroll
  for (int n = 0; n < 4; ++n) bs[n] = bias[bn0 + wn * 64 + n * 16 + r16];
  const int rb = (lane >> 4) * 4;
#pragma unroll
  for (int m = 0; m < 8; ++m)
#pragma unroll
    for (int i = 0; i < 4; ++i) {
      const size_t row = (size_t)bm0 + wm * 128 + m * 16 + rb + i;
#pragma unroll
      for (int n = 0; n < 4; ++n) {
        const int col = bn0 + wn * 64 + n * 16 + r16;
        float v = acc[m][n][i] + bs[n];
        if constexpr (OUTF32)
          ((float*)Cp)[row * GN + col] = v;
        else
          ((unsigned short*)Cp)[row * GN + col] = f2bf(v);
      }
    }
}

// ---------------- fallback 128^2 GEMM (fp32 A, reg-staged) ----------------
template <bool AF32, bool OUTF32>
__global__ __launch_bounds__(256)
void gemm_bt(const void* __restrict__ Ap, const unsigned short* __restrict__ Bp,
             const float* __restrict__ bias, void* __restrict__ Cp) {
  constexpr int BM = 128, BN = 128, BK = 32;
  __shared__ unsigned short As[BM * BK];
  __shared__ unsigned short Bs[BN * BK];

  const int tid  = threadIdx.x;
  const int lane = tid & 63;
  const int wv   = tid >> 6;

  constexpr int NWG = (GM / BM) * (GN / BN);  // 2048
  int bid = (int)blockIdx.x;
  bid = (bid & 7) * (NWG >> 3) + (bid >> 3);
  const int mt = bid >> 4;
  const int nt = bid & 15;
  const int bm0 = mt * BM, bn0 = nt * BN;

  const int wr = wv >> 1, wc = wv & 1;
  const int r16 = lane & 15, kblk = lane >> 4;

  f32x4 acc[4][4] = {};

  const int srow = lane >> 2;
  const int scol = (lane & 3) * 8;

  for (int k0 = 0; k0 < GK; k0 += BK) {
    if (k0) __syncthreads();
#pragma unroll
    for (int c = 0; c < 2; ++c) {
      const int chunk = wv * 2 + c;
      const unsigned short* g =
          Bp + (size_t)(bn0 + chunk * 16 + srow) * GK + (k0 + scol);
      gload16(g, &Bs[chunk * 512]);
    }
    if constexpr (AF32) {
      const float* Af = (const float*)Ap;
      const int arow = tid >> 1;
      const int ak = (tid & 1) * 16;
      const f32x4* g4 = (const f32x4*)(Af + (size_t)(bm0 + arow) * GK + k0 + ak);
      f32x4 f[4];
      f[0] = g4[0]; f[1] = g4[1]; f[2] = g4[2]; f[3] = g4[3];
      ushort8 p0, p1;
#pragma unroll
      for (int j = 0; j < 8; ++j) {
        p0[j] = f2bf(f[j >> 2][j & 3]);
        p1[j] = f2bf(f[2 + (j >> 2)][j & 3]);
      }
      *(ushort8*)&As[arow * BK + ak]     = p0;
      *(ushort8*)&As[arow * BK + ak + 8] = p1;
    } else {
#pragma unroll
      for (int c = 0; c < 2; ++c) {
        const int chunk = wv * 2 + c;
        const unsigned short* g = (const unsigned short*)Ap +
            (size_t)(bm0 + chunk * 16 + srow) * GK + (k0 + scol);
        gload16(g, &As[chunk * 512]);
      }
    }
    __syncthreads();
    short8 a_f[4], b_f[4];
#pragma unroll
    for (int m = 0; m < 4; ++m)
      a_f[m] = *(const short8*)&As[(wr * 64 + m * 16 + r16) * BK + kblk * 8];
#pragma unroll
    for (int n = 0; n < 4; ++n)
      b_f[n] = *(const short8*)&Bs[(wc * 64 + n * 16 + r16) * BK + kblk * 8];
#pragma unroll
    for (int m = 0; m < 4; ++m)
#pragma unroll
      for (int n = 0; n < 4; ++n)
        acc[m][n] = __builtin_amdgcn_mfma_f32_16x16x32_bf16(a_f[m], b_f[n],
                                                            acc[m][n], 0, 0, 0);
  }
  const int rb = (lane >> 4) * 4;
#pragma unroll
  for (int m = 0; m < 4; ++m)
#pragma unroll
    for (int i = 0; i < 4; ++i) {
      const size_t row = bm0 + wr * 64 + m * 16 + rb + i;
#pragma unroll
      for (int n = 0; n < 4; ++n) {
        const int col = bn0 + wc * 64 + n * 16 + r16;
        float v = acc[m][n][i] + bias[col];
        if constexpr (OUTF32)
          ((float*)Cp)[row * GN + col] = v;
        else
          ((unsigned short*)Cp)[row * GN + col] = f2bf(v);
      }
    }
}

// ---------------- per-position attention (softmax over heads) -------------
__global__ __launch_bounds__(256)
void attn_kernel(const unsigned short* __restrict__ Qb,
                 const unsigned short* __restrict__ Kb,
                 const unsigned short* __restrict__ Vb,
                 float* __restrict__ attnOut,
                 unsigned short* __restrict__ X2) {
  __shared__ float qf[16 * 128];
  __shared__ float kf[16 * 132];
  __shared__ float vf[16 * 128];
  __shared__ float sc[256];

  const int t = threadIdx.x;
  const int p = blockIdx.x;
  const size_t rowoff = (size_t)p * DIM;

  {
    const int e = t * 8;
    u16x8 qv = *(const u16x8*)(Qb + rowoff + e);
    u16x8 kv = *(const u16x8*)(Kb + rowoff + e);
    u16x8 vv = *(const u16x8*)(Vb + rowoff + e);
    const int r = t >> 4, c = (t & 15) * 8;
#pragma unroll
    for (int j = 0; j < 8; ++j) qf[r * 128 + c + j] = bf2f(qv[j]);
#pragma unroll
    for (int j = 0; j < 8; ++j) kf[r * 132 + c + j] = bf2f(kv[j]);
#pragma unroll
    for (int j = 0; j < 8; ++j) vf[r * 128 + c + j] = bf2f(vv[j]);
  }
  __syncthreads();

  const int i = t >> 4, j = t & 15;
  float s = 0.f;
#pragma unroll
  for (int d4 = 0; d4 < 32; ++d4) {
    f32x4 q4 = *(const f32x4*)&qf[i * 128 + d4 * 4];
    f32x4 k4 = *(const f32x4*)&kf[j * 132 + d4 * 4];
    s = fmaf(q4[0], k4[0], fmaf(q4[1], k4[1], fmaf(q4[2], k4[2], fmaf(q4[3], k4[3], s))));
  }
  s *= 0.08838834764831845f;

  float mx = s;
#pragma unroll
  for (int off = 8; off; off >>= 1) mx = fmaxf(mx, __shfl_xor(mx, off, 16));
  float ex = __expf(s - mx);
  float sum = ex;
#pragma unroll
  for (int off = 8; off; off >>= 1) sum += __shfl_xor(sum, off, 16);
  float a = ex / sum;

  attnOut[(size_t)p * 256 + t] = a;
  sc[t] = a;
  __syncthreads();

  const int dh0 = j * 8;
  float o[8] = {};
#pragma unroll
  for (int jj = 0; jj < 16; ++jj) {
    float aij = sc[i * 16 + jj];
#pragma unroll
    for (int e2 = 0; e2 < 8; ++e2)
      o[e2] = fmaf(aij, vf[jj * 128 + dh0 + e2], o[e2]);
  }
  const int b = p >> 12, spos = p & 4095;
  const int row = i * 256 + (spos >> 4);
  const int col = ((spos & 15) << 7) + dh0;
  ushort8 pk;
#pragma unroll
  for (int e2 = 0; e2 < 8; ++e2) pk[e2] = f2bf(o[e2]);
  *(ushort8*)(X2 + (size_t)b * (SEQ * DIM) + (size_t)row * DIM + col) = pk;
}

// ---------------------------------------------------------------------------
extern "C" void kernel_launch(void* const* d_in, const int* in_sizes, int n_in,
                              void* d_out, int out_size, void* d_ws,
                              size_t ws_size, hipStream_t stream) {
  const float* q  = (const float*)d_in[0];
  const float* k  = (const float*)d_in[1];
  const float* v  = (const float*)d_in[2];
  const float* Wq = (const float*)d_in[3];
  const float* bq = (const float*)d_in[4];
  const float* Wk = (const float*)d_in[5];
  const float* bk = (const float*)d_in[6];
  const float* Wv = (const float*)d_in[7];
  const float* bv = (const float*)d_in[8];
  const float* Wo = (const float*)d_in[9];
  const float* bo = (const float*)d_in[10];

  const size_t NE = (size_t)GM * GK;
  const size_t WE = (size_t)GK * GN;

  unsigned short* ws16 = (unsigned short*)d_ws;
  unsigned short* Wq_b = ws16;
  unsigned short* Wk_b = Wq_b + WE;
  unsigned short* Wv_b = Wk_b + WE;
  unsigned short* Wo_b = Wv_b + WE;
  unsigned short* Qb   = Wo_b + WE;
  unsigned short* Kb   = Qb + NE;
  unsigned short* Vb   = Kb + NE;
  unsigned short* X2   = Vb + NE;
  unsigned short* Qin  = X2 + NE;
  unsigned short* Kin  = Qin + NE;
  unsigned short* Vin  = Kin + NE;

  const size_t need_small = (4 * WE + 4 * NE) * 2;
  const size_t need_big   = need_small + 3 * NE * 2;
  const bool big = ws_size >= need_big;

  float* outMain = (float*)d_out;
  float* attnOut = outMain + (size_t)GM * GN;

  cvt_f32_bf16<<<WE / 1024, 256, 0, stream>>>(Wq, Wq_b, (int)WE);
  cvt_f32_bf16<<<WE / 1024, 256, 0, stream>>>(Wk, Wk_b, (int)WE);
  cvt_f32_bf16<<<WE / 1024, 256, 0, stream>>>(Wv, Wv_b, (int)WE);
  cvt_f32_bf16<<<WE / 1024, 256, 0, stream>>>(Wo, Wo_b, (int)WE);

  constexpr int G256 = (GM / 256) * (GN / 256);   // 512
  constexpr int G128 = (GM / 128) * (GN / 128);   // 2048

  if (big) {
    cvt_f32_bf16<<<NE / 1024, 256, 0, stream>>>(q, Qin, (int)NE);
    cvt_f32_bf16<<<NE / 1024, 256, 0, stream>>>(k, Kin, (int)NE);
    cvt_f32_bf16<<<NE / 1024, 256, 0, stream>>>(v, Vin, (int)NE);
    gemm256<false><<<G256, 512, 0, stream>>>(Qin, Wq_b, bq, Qb);
    gemm256<false><<<G256, 512, 0, stream>>>(Kin, Wk_b, bk, Kb);
    gemm256<false><<<G256, 512, 0, stream>>>(Vin, Wv_b, bv, Vb);
  } else {
    gemm_bt<true, false><<<G128, 256, 0, stream>>>(q, Wq_b, bq, Qb);
    gemm_bt<true, false><<<G128, 256, 0, stream>>>(k, Wk_b, bk, Kb);
    gemm_bt<true, false><<<G128, 256, 0, stream>>>(v, Wv_b, bv, Vb);
  }

  attn_kernel<<<GM, 256, 0, stream>>>(Qb, Kb, Vb, attnOut, X2);

  gemm256<true><<<G256, 512, 0, stream>>>(X2, Wo_b, bo, outMain);
}